// Round 5
// baseline (252.596 us; speedup 1.0000x reference)
//
#include <hip/hip_runtime.h>
#include <hip/hip_bf16.h>

// Inputs: 0 features[N,64] f32 | 1 receivers[E] i32 | 2 relpos[E,2] f32
//         3 window_support[1] f32 | 4 senders[E] i32 | 5 kernel[4,2,64,64] f32
//         6 bias[64] f32   -> out [N,64] f32

#define T_TAPS 16

typedef unsigned short u16;
typedef short s16x8 __attribute__((ext_vector_type(8)));
typedef u16 u16x8 __attribute__((ext_vector_type(8)));
typedef float f32x4 __attribute__((ext_vector_type(4)));

static __device__ __forceinline__ u16 f2bf(float x) {
    union { float f; unsigned u; } v; v.f = x;
    unsigned r = v.u + 0x7FFF + ((v.u >> 16) & 1);
    return (u16)(r >> 16);
}

// ---------------- CSR build ----------------
__global__ __launch_bounds__(256) void ascc_hist(
    int* __restrict__ cnt, const int* __restrict__ receivers, int E)
{
    int e = blockIdx.x * 256 + threadIdx.x;
    if (e < E) atomicAdd(&cnt[receivers[e]], 1);
}

__global__ __launch_bounds__(256) void ascc_scan1(
    int* __restrict__ bsum, const int* __restrict__ cnt, int Nn)
{
    __shared__ int red[256];
    int i0 = blockIdx.x * 2048 + threadIdx.x * 8;
    int s = 0;
    #pragma unroll
    for (int k = 0; k < 8; ++k) { int i = i0 + k; if (i < Nn) s += cnt[i]; }
    red[threadIdx.x] = s;
    __syncthreads();
    #pragma unroll
    for (int d = 128; d > 0; d >>= 1) {
        if (threadIdx.x < d) red[threadIdx.x] += red[threadIdx.x + d];
        __syncthreads();
    }
    if (threadIdx.x == 0) bsum[blockIdx.x] = red[0];
}

__global__ __launch_bounds__(256) void ascc_scan2(
    int* __restrict__ boff, int* __restrict__ off,
    const int* __restrict__ bsum, int NB, int Nn)
{
    __shared__ int s[256];
    int x = (threadIdx.x < NB) ? bsum[threadIdx.x] : 0;
    s[threadIdx.x] = x;
    __syncthreads();
    #pragma unroll
    for (int d = 1; d < 256; d <<= 1) {
        int t = (threadIdx.x >= d) ? s[threadIdx.x - d] : 0;
        __syncthreads();
        s[threadIdx.x] += t;
        __syncthreads();
    }
    if (threadIdx.x < NB) boff[threadIdx.x] = s[threadIdx.x] - x;
    if (threadIdx.x == 255) off[Nn] = s[255];
}

__global__ __launch_bounds__(256) void ascc_scan3(
    int* __restrict__ off, int* __restrict__ cur,
    const int* __restrict__ cnt, const int* __restrict__ boff, int Nn)
{
    __shared__ int s[256];
    int i0 = blockIdx.x * 2048 + threadIdx.x * 8;
    int x[8]; int ts = 0;
    #pragma unroll
    for (int k = 0; k < 8; ++k) { int i = i0 + k; x[k] = (i < Nn) ? cnt[i] : 0; ts += x[k]; }
    s[threadIdx.x] = ts;
    __syncthreads();
    #pragma unroll
    for (int d = 1; d < 256; d <<= 1) {
        int t = (threadIdx.x >= d) ? s[threadIdx.x - d] : 0;
        __syncthreads();
        s[threadIdx.x] += t;
        __syncthreads();
    }
    int run = boff[blockIdx.x] + s[threadIdx.x] - ts;
    #pragma unroll
    for (int k = 0; k < 8; ++k) {
        int i = i0 + k;
        if (i < Nn) { off[i] = run; cur[i] = run; }
        run += x[k];
    }
}

// ---------- fused fill+prep: claim sorted slot, write edge record -----------
__global__ __launch_bounds__(256) void ascc_fillprep(
    int* __restrict__ ssend, float4* __restrict__ swx, float4* __restrict__ swy,
    int* __restrict__ cur, const int* __restrict__ receivers,
    const float* __restrict__ relpos, const float* __restrict__ wsup,
    const int* __restrict__ senders, int E)
{
    int e = blockIdx.x * 256 + threadIdx.x;
    if (e >= E) return;
    int p = atomicAdd(&cur[receivers[e]], 1);

    float ws = wsup[0];
    float2 rp = *(const float2*)(relpos + 2 * e);
    float u0 = fminf(fmaxf(rp.x / ws, -1.f), 1.f);
    float u1 = fminf(fmaxf(rp.y / ws, -1.f), 1.f);
    float gx = (u0 + 1.f) * 1.5f;
    float gy = (u1 + 1.f) * 1.5f;
    float x0f = fminf(fmaxf(floorf(gx), 0.f), 2.f);
    float y0f = fminf(fmaxf(floorf(gy), 0.f), 2.f);
    float fx = gx - x0f, fy = gy - y0f;
    int x0i = (int)x0f, y0i = (int)y0f;
    float r2 = u0 * u0 + u1 * u1;
    float win = fmaxf(1.f - r2, 0.f);
    win = win * win * win;
    float wx[4], wy[4];
    #pragma unroll
    for (int k = 0; k < 4; ++k)
        wx[k] = win * ((k == x0i) ? (1.f - fx) : ((k == x0i + 1) ? fx : 0.f));
    #pragma unroll
    for (int k = 0; k < 4; ++k)
        wy[k] = (k == y0i) ? (1.f - fy) : ((k == y0i + 1) ? fy : 0.f);

    ssend[p] = senders[e];
    swx[p] = make_float4(wx[0], wx[1], wx[2], wx[3]);
    swy[p] = make_float4(wy[0], wy[1], wy[2], wy[3]);
}

// ---------------- kernel tensor: antisymmetrize + transpose -> bf16 --------
// KfT[o][k], k = t*64+i ; t=x*4+y ; y<2: +kern[x][y][i][o] ; else -kern[3-x][3-y][i][o]
__global__ __launch_bounds__(256) void ascc_kft(
    u16* __restrict__ KfT, const float* __restrict__ kern)
{
    int idx = blockIdx.x * 256 + threadIdx.x;   // 64*1024
    int o = idx >> 10;
    int k = idx & 1023;
    int t = k >> 6, i = k & 63;
    int x = t >> 2, y = t & 3;
    float val;
    if (y < 2) val =  kern[(((x * 2 + y) * 64) + i) * 64 + o];
    else       val = -kern[((((3 - x) * 2 + (3 - y)) * 64) + i) * 64 + o];
    KfT[(size_t)o * 1024 + k] = f2bf(val);
}

// ---------------- FUSED: accumulate A-tile in LDS, MFMA, store out ---------
// Block: 256 thr / 4 waves, 32 receivers. Wave w accumulates receivers
// w*8..w*8+7 (lane = channel, acc[16] taps in VGPR, masked 8-edge groups),
// writes bf16 rows into XOR-swizzled LDS A[32][1024]. Then all 4 waves MFMA
// A-tile against KfT (staged in 16KB LDS chunks) and store out directly.
__global__ __launch_bounds__(256, 2) void ascc_fused(
    float* __restrict__ out,
    const float* __restrict__ features,
    const int* __restrict__ off,
    const int* __restrict__ ssend,
    const float4* __restrict__ swx,
    const float4* __restrict__ swy,
    const u16* __restrict__ KfT,
    const float* __restrict__ bias,
    int Nn)
{
    __shared__ u16 Al[32 * 1024];   // 64 KB, row stride 2048 B, XOR-swizzled
    __shared__ u16 Bl[64 * 128];    // 16 KB chunk of KfT, XOR-swizzled

    const int tid  = threadIdx.x;
    const int lane = tid & 63;
    const int w    = tid >> 6;        // 0..3
    const int n0   = blockIdx.x * 32;

    // ---------------- phase 1: accumulate ----------------
    #pragma unroll 1
    for (int rr = 0; rr < 8; ++rr) {
        int row = (w << 3) + rr;
        int r = n0 + row;
        if (r >= Nn) continue;

        float acc[T_TAPS];
        #pragma unroll
        for (int t = 0; t < T_TAPS; ++t) acc[t] = 0.f;

        int j0 = off[r], j1 = off[r + 1];
        #pragma unroll 1
        for (int j = j0; j < j1; j += 8) {
            int   sj[8];
            float4 wxv[8], wyv[8];
            float gq[8];
            // issue all loads up front (8-deep MLP)
            #pragma unroll
            for (int q = 0; q < 8; ++q) {
                int jj = j + q;
                int jc = (jj < j1) ? jj : (j1 - 1);
                sj[q]  = ssend[jc];
                wxv[q] = swx[jc];
                wyv[q] = swy[jc];
            }
            #pragma unroll
            for (int q = 0; q < 8; ++q) {
                float g = features[(size_t)sj[q] * 64 + lane];
                gq[q] = (j + q < j1) ? g : 0.f;
            }
            #pragma unroll
            for (int q = 0; q < 8; ++q) {
                float wxa[4] = {wxv[q].x, wxv[q].y, wxv[q].z, wxv[q].w};
                float wyg[4] = {wyv[q].x * gq[q], wyv[q].y * gq[q],
                                wyv[q].z * gq[q], wyv[q].w * gq[q]};
                #pragma unroll
                for (int t = 0; t < T_TAPS; ++t)
                    acc[t] += wxa[t >> 2] * wyg[t & 3];
            }
        }

        // write row to LDS (bf16), swizzled; stays within each 128B tap granule
        int rowbyte = row << 11;
        int sw = (row & 7) << 4;
        #pragma unroll
        for (int t = 0; t < T_TAPS; ++t) {
            int byte = (rowbyte + (t << 7) + (lane << 1)) ^ sw;
            *(u16*)((char*)Al + byte) = f2bf(acc[t]);
        }
    }

    // ---------------- phase 2: MFMA against KfT chunks ----------------
    const int stripe  = w >> 1;       // 0..1 -> rows stripe*16..+15
    const int colhalf = w & 1;        // 0..1 -> cols colhalf*32..+31
    f32x4 acc2[2] = {};

    const int arow  = (stripe << 4) + (lane & 15);
    const int abase = arow << 11;
    const int asw   = (arow & 7) << 4;
    const int kfrag = (lane >> 4) << 3;   // 8-elem k sub-offset

    for (int kc = 0; kc < 1024; kc += 128) {
        __syncthreads();   // first iter: phase1->2 barrier; later: guard Bl reuse
        // stage B chunk: KfT[0..63][kc..kc+128)
        {
            int brow = tid >> 2, seg = tid & 3;
            const u16* src = KfT + (size_t)brow * 1024 + kc + seg * 32;
            int dbase = brow << 8;
            int bsw = (brow & 7) << 4;
            #pragma unroll
            for (int g2 = 0; g2 < 4; ++g2) {
                u16x8 v = *(const u16x8*)(src + g2 * 8);
                int byte = (dbase + (seg << 6) + (g2 << 4)) ^ bsw;
                *(u16x8*)((char*)Bl + byte) = v;
            }
        }
        __syncthreads();
        #pragma unroll
        for (int ks = 0; ks < 4; ++ks) {
            int koff = (kc + (ks << 5) + kfrag) << 1;
            s16x8 af = *(const s16x8*)((char*)Al + ((abase + koff) ^ asw));
            #pragma unroll
            for (int t = 0; t < 2; ++t) {
                int brow2 = (colhalf << 5) + (t << 4) + (lane & 15);
                int bbyte = ((brow2 << 8) + (((ks << 5) + kfrag) << 1)) ^ ((brow2 & 7) << 4);
                s16x8 bf = *(const s16x8*)((char*)Bl + bbyte);
                acc2[t] = __builtin_amdgcn_mfma_f32_16x16x32_bf16(af, bf, acc2[t], 0, 0, 0);
            }
        }
    }

    // ---------------- epilogue ----------------
    int rbase = n0 + (stripe << 4) + ((lane >> 4) << 2);
    #pragma unroll
    for (int t = 0; t < 2; ++t) {
        int col = (colhalf << 5) + (t << 4) + (lane & 15);
        float bv = bias[col];
        #pragma unroll
        for (int reg = 0; reg < 4; ++reg) {
            int n = rbase + reg;
            if (n < Nn) out[(size_t)n * 64 + col] = acc2[t][reg] + bv;
        }
    }
}

extern "C" void kernel_launch(void* const* d_in, const int* in_sizes, int n_in,
                              void* d_out, int out_size, void* d_ws, size_t ws_size,
                              hipStream_t stream) {
    const float* features  = (const float*)d_in[0];
    const int*   receivers = (const int*)d_in[1];
    const float* relpos    = (const float*)d_in[2];
    const float* wsup      = (const float*)d_in[3];
    const int*   senders   = (const int*)d_in[4];
    const float* kern      = (const float*)d_in[5];
    const float* bias      = (const float*)d_in[6];
    float* out = (float*)d_out;

    const int Nn = in_sizes[0] / 64;
    const int E  = in_sizes[1];
    const int NB = (Nn + 2047) / 2048;   // scan blocks (<=256)

    // ws: off[N+1] | cur[N] | bsum[NB] | boff[NB] | ssend[E] | swx[E] | swy[E] | KfT
    char* wp = (char*)d_ws;
    size_t p = 0;
    auto take = [&](size_t bytes) { char* q = wp + p; p = (p + bytes + 255) & ~(size_t)255; return q; };
    int*    off   = (int*)take((size_t)(Nn + 1) * 4);
    int*    cur   = (int*)take((size_t)Nn * 4);
    int*    bsum  = (int*)take((size_t)NB * 4);
    int*    boff  = (int*)take((size_t)NB * 4);
    int*    ssend = (int*)take((size_t)E * 4);
    float4* swx   = (float4*)take((size_t)E * 16);
    float4* swy   = (float4*)take((size_t)E * 16);
    u16*    KfT   = (u16*)take((size_t)64 * 1024 * 2);
    (void)ws_size;

    dim3 ge((E + 255) / 256);

    ascc_kft<<<dim3(256), dim3(256), 0, stream>>>(KfT, kern);

    hipMemsetAsync(cur, 0, (size_t)Nn * sizeof(int), stream);
    ascc_hist<<<ge, dim3(256), 0, stream>>>(cur, receivers, E);
    ascc_scan1<<<dim3(NB), dim3(256), 0, stream>>>(bsum, cur, Nn);
    ascc_scan2<<<dim3(1), dim3(256), 0, stream>>>(boff, off, bsum, NB, Nn);
    ascc_scan3<<<dim3(NB), dim3(256), 0, stream>>>(off, cur, cur, boff, Nn);
    ascc_fillprep<<<ge, dim3(256), 0, stream>>>(
        ssend, swx, swy, cur, receivers, relpos, wsup, senders, E);

    ascc_fused<<<dim3((Nn + 31) / 32), dim3(256), 0, stream>>>(
        out, features, off, ssend, swx, swy, KfT, bias, Nn);
}